// Round 7
// baseline (540.848 us; speedup 1.0000x reference)
//
#include <hip/hip_runtime.h>

// DepthScaleCorrector — L3-blocked group pipeline.
// nsd (16,4,768,1024) f32, sp (16,1,768,1024) f32.
// Outputs (concat f32): corrected 50331648 | best_corrected 12582912 | best_idx 16.
//
// 16 batches processed in 4 groups of 4 so each group's input (63 MB) stays
// L3-resident between its reduce pass and its apply pass (63R + 63W << 256 MB L3).
//   memset   : zero 4 group counters (16 B)
//   k_reduce : 23 masked stats/block; LAST block (atomic counter) reduces partials,
//              solves 2x2, analytic MSE + clip-proof, argmin -> wsf/bidx/flags/esum
//   k_apply  : corrected = clip(a*x+b); regular loads (L3-hot), NT stores;
//              fast path writes out_best inline; slow path exact err atomics
//   k_best   : fast batches early-exit; slow-path fallback argmin + copy

typedef float f4 __attribute__((ext_vector_type(4)));

#define HWPIX (768 * 1024)
#define HW4   (HWPIX / 4)      // 196608 f4 per (b,c)
#define NBG 4                  // batches per group
#define GBLK 1024              // blocks per group dispatch
#define BPB (GBLK / NBG)       // 256 blocks per batch
#define F4PB (HW4 / BPB)       // 768 f4 per (b,c) per block
#define GITERS (F4PB / 256)    // 3
#define VALID_THR 1e-6f
#define MAXD 20.0f
#define NSTAT 23               // 0:n 1:y 2:y2 3+c:x 7+c:x2 11+c:xy 15+c:xmin 19+c:xmax

__device__ inline double wred_sum(double v) {
#pragma unroll
    for (int o = 32; o > 0; o >>= 1) v += __shfl_down(v, o, 64);
    return v;
}
__device__ inline double wred_min(double v) {
#pragma unroll
    for (int o = 32; o > 0; o >>= 1) v = fmin(v, __shfl_down(v, o, 64));
    return v;
}
__device__ inline double wred_max(double v) {
#pragma unroll
    for (int o = 32; o > 0; o >>= 1) v = fmax(v, __shfl_down(v, o, 64));
    return v;
}

// ---------------- pass 1: masked stats + fused finisher ----------------
__global__ __launch_bounds__(256) void k_reduce(const f4* __restrict__ nsd,
                                                const f4* __restrict__ sp,
                                                double* __restrict__ part,
                                                int g0, int* __restrict__ counter,
                                                float* __restrict__ wsf,
                                                double* __restrict__ wsn,
                                                int* __restrict__ bidx,
                                                int* __restrict__ flags,
                                                double* __restrict__ esum,
                                                float* __restrict__ out_idx) {
    const int blk = blockIdx.x;
    const int bl = blk >> 8;            // local batch 0..3
    const int chunk = blk & (BPB - 1);
    const int b = g0 + bl;
    const int t = threadIdx.x;
    const int sbase = b * HW4 + chunk * F4PB;

    float lnv = 0.f, lyv = 0.f, ly2 = 0.f;
    float lx[4] = {0, 0, 0, 0}, lx2[4] = {0, 0, 0, 0}, lxy[4] = {0, 0, 0, 0};
    float lmn[4] = {INFINITY, INFINITY, INFINITY, INFINITY};
    float lmx[4] = {-INFINITY, -INFINITY, -INFINITY, -INFINITY};
#pragma unroll
    for (int i = 0; i < GITERS; i++) {
        const int o = i * 256 + t;
        f4 s4 = sp[sbase + o];
        float mv[4], svm[4];
#pragma unroll
        for (int l = 0; l < 4; l++) {
            float sv = s4[l];
            mv[l] = (sv > VALID_THR && sv <= MAXD) ? 1.0f : 0.0f;
            svm[l] = sv * mv[l];
            lnv += mv[l];
            lyv += svm[l];
            ly2 = fmaf(sv * sv, mv[l], ly2);
        }
#pragma unroll
        for (int c = 0; c < 4; c++) {
            f4 x4 = nsd[(b * 4 + c) * HW4 + chunk * F4PB + o];
#pragma unroll
            for (int l = 0; l < 4; l++) {
                float xv = x4[l];
                lx[c]  = fmaf(xv, mv[l], lx[c]);
                lx2[c] = fmaf(xv * xv, mv[l], lx2[c]);
                lxy[c] = fmaf(xv, svm[l], lxy[c]);
                lmn[c] = fminf(lmn[c], mv[l] != 0.f ? xv : INFINITY);
                lmx[c] = fmaxf(lmx[c], mv[l] != 0.f ? xv : -INFINITY);
            }
        }
    }

    double vals[NSTAT] = {(double)lnv, (double)lyv, (double)ly2,
                          (double)lx[0],  (double)lx[1],  (double)lx[2],  (double)lx[3],
                          (double)lx2[0], (double)lx2[1], (double)lx2[2], (double)lx2[3],
                          (double)lxy[0], (double)lxy[1], (double)lxy[2], (double)lxy[3],
                          (double)lmn[0], (double)lmn[1], (double)lmn[2], (double)lmn[3],
                          (double)lmx[0], (double)lmx[1], (double)lmx[2], (double)lmx[3]};
    __shared__ double red[4][NSTAT];
    const int wv = t >> 6, lane = t & 63;
#pragma unroll
    for (int j = 0; j < NSTAT; j++) {
        double r = (j < 15) ? wred_sum(vals[j])
                 : (j < 19) ? wred_min(vals[j])
                            : wred_max(vals[j]);
        if (lane == 0) red[wv][j] = r;
    }
    __syncthreads();
    if (t < NSTAT) {
        double a0 = red[0][t], a1 = red[1][t], a2 = red[2][t], a3 = red[3][t];
        double r = (t < 15) ? (a0 + a1 + a2 + a3)
                 : (t < 19) ? fmin(fmin(a0, a1), fmin(a2, a3))
                            : fmax(fmax(a0, a1), fmax(a2, a3));
        part[t * GBLK + blk] = r;
    }
    __threadfence();
    __syncthreads();

    __shared__ int lastFlag;
    if (t == 0) {
        int old = __hip_atomic_fetch_add(&counter[g0 >> 2], 1,
                                         __ATOMIC_ACQ_REL, __HIP_MEMORY_SCOPE_AGENT);
        lastFlag = (old == GBLK - 1) ? 1 : 0;
    }
    __syncthreads();
    if (!lastFlag) return;
    __threadfence();   // acquire: invalidate stale lines before reading peers' partials

    // ---- finisher: reduce 23 stats x 4 batches (2 threads per task) ----
    __shared__ double sred[NSTAT][NBG];
    if (t < NSTAT * NBG * 2) {          // 184 threads
        const int task = t >> 1, p = t & 1;
        const int j = task >> 2;        // stat
        const int bb = task & 3;        // local batch
        const double* src = part + j * GBLK + bb * BPB + p * 128;
        double acc;
        if (j < 15) {
            acc = 0.0;
#pragma unroll 8
            for (int k = 0; k < 128; k++) acc += src[k];
            acc += __shfl_down(acc, 1, 64);
        } else if (j < 19) {
            acc = INFINITY;
#pragma unroll 8
            for (int k = 0; k < 128; k++) acc = fmin(acc, src[k]);
            acc = fmin(acc, __shfl_down(acc, 1, 64));
        } else {
            acc = -INFINITY;
#pragma unroll 8
            for (int k = 0; k < 128; k++) acc = fmax(acc, src[k]);
            acc = fmax(acc, __shfl_down(acc, 1, 64));
        }
        if (p == 0) sred[j][bb] = acc;
    }
    __syncthreads();

    __shared__ double smse[NBG][4];
    __shared__ int snoclip[NBG][4];
    if (t < NBG * 4) {                  // 16 threads: (local batch, channel)
        const int bb = t >> 2, c = t & 3;
        const int gb = g0 + bb;
        double n   = sred[0][bb];
        double y   = sred[1][bb];
        double y2  = sred[2][bb];
        double x   = sred[3 + c][bb];
        double x2  = sred[7 + c][bb];
        double xy  = sred[11 + c][bb];
        double xmn = sred[15 + c][bb];
        double xmx = sred[19 + c][bb];
        double det = n * x2 - x * x;
        bool ok = (n >= 10.0) && (fabs(det) >= 1e-8);
        double sdet = ok ? det : 1.0;
        double ad = ok ? (n * xy - x * y) / sdet : 1.0;
        double bd = ok ? (x2 * y - x * xy) / sdet : 0.0;
        float af = (float)ad, bf = (float)bd;
        wsf[gb * 4 + c] = af;
        wsf[64 + gb * 4 + c] = bf;
        if (c == 0) wsn[gb] = n;
        esum[gb * 4 + c] = 0.0;

        double mse;
        int noclip;
        if (n <= 0.0) {
            mse = INFINITY;
            noclip = 1;
        } else {
            double A = (double)af, B = (double)bf;
            double e0 = A * xmn + B, e1 = A * xmx + B;
            double clo = fmin(e0, e1), chi = fmax(e0, e1);
            noclip = (clo >= 0.0 && chi <= (double)MAXD) ? 1 : 0;
            mse = (A * A * x2 + 2.0 * A * B * x + B * B * n
                   - 2.0 * A * xy - 2.0 * B * y + y2) / fmax(n, 1.0);
        }
        smse[bb][c] = mse;
        snoclip[bb][c] = noclip;
    }
    __syncthreads();

    if (t < NBG) {
        const int gb = g0 + t;
        int fast = snoclip[t][0] & snoclip[t][1] & snoclip[t][2] & snoclip[t][3];
        flags[gb] = fast ? 0 : 1;
        if (fast) {
            double best = INFINITY;
            int bc = 0;
            for (int cc = 0; cc < 4; cc++) {
                double m = smse[t][cc];
                if (m < best) { best = m; bc = cc; }
            }
            bidx[gb] = bc;
            out_idx[gb] = (float)bc;
        }
    }
}

// ---------------- pass 2: apply (group) ----------------
__global__ __launch_bounds__(256) void k_apply(const f4* __restrict__ nsd,
                                               const f4* __restrict__ sp,
                                               const float* __restrict__ wsf,
                                               const int* __restrict__ bidx,
                                               const int* __restrict__ flags,
                                               double* __restrict__ esum,
                                               f4* __restrict__ out_corr,
                                               f4* __restrict__ out_best,
                                               int g0) {
    const int blk = blockIdx.x;
    const int bl = blk >> 8;
    const int chunk = blk & (BPB - 1);
    const int b = g0 + bl;
    const int t = threadIdx.x;
    float sc[4], bi[4];
#pragma unroll
    for (int c = 0; c < 4; c++) {
        sc[c] = wsf[b * 4 + c];
        bi[c] = wsf[64 + b * 4 + c];
    }
    const int sbase = b * HW4 + chunk * F4PB;

    if (flags[b] == 0) {
        const int cbest = bidx[b];
#pragma unroll
        for (int i = 0; i < GITERS; i++) {
            const int o = i * 256 + t;
#pragma unroll
            for (int c = 0; c < 4; c++) {
                const int off = (b * 4 + c) * HW4 + chunk * F4PB + o;
                f4 x4 = nsd[off];        // L3-hot (just read by k_reduce of this group)
                f4 o4;
#pragma unroll
                for (int l = 0; l < 4; l++)
                    o4[l] = fminf(fmaxf(fmaf(sc[c], x4[l], bi[c]), 0.0f), MAXD);
                __builtin_nontemporal_store(o4, &out_corr[off]);
                if (c == cbest)
                    __builtin_nontemporal_store(o4, &out_best[sbase + o]);
            }
        }
        return;
    }

    // slow path (clipping detected): exact per-pixel err
    float lerr[4] = {0, 0, 0, 0};
#pragma unroll
    for (int i = 0; i < GITERS; i++) {
        const int o = i * 256 + t;
        f4 s4 = sp[sbase + o];
        float mv[4];
#pragma unroll
        for (int l = 0; l < 4; l++)
            mv[l] = (s4[l] > VALID_THR && s4[l] <= MAXD) ? 1.0f : 0.0f;
#pragma unroll
        for (int c = 0; c < 4; c++) {
            const int off = (b * 4 + c) * HW4 + chunk * F4PB + o;
            f4 x4 = nsd[off];
            f4 o4;
#pragma unroll
            for (int l = 0; l < 4; l++)
                o4[l] = fminf(fmaxf(fmaf(sc[c], x4[l], bi[c]), 0.0f), MAXD);
            __builtin_nontemporal_store(o4, &out_corr[off]);
#pragma unroll
            for (int l = 0; l < 4; l++) {
                float d = o4[l] - s4[l];
                lerr[c] = fmaf(d * d, mv[l], lerr[c]);
            }
        }
    }
    __shared__ double red[4][4];
    const int wv = t >> 6, lane = t & 63;
#pragma unroll
    for (int j = 0; j < 4; j++) {
        double r = wred_sum((double)lerr[j]);
        if (lane == 0) red[wv][j] = r;
    }
    __syncthreads();
    if (t < 4)
        atomicAdd(&esum[b * 4 + t], red[0][t] + red[1][t] + red[2][t] + red[3][t]);
}

// ---------------- slow-path best copy ----------------
__global__ __launch_bounds__(256) void k_best(const f4* __restrict__ corr,
                                              const int* __restrict__ flags,
                                              const double* __restrict__ esum,
                                              const double* __restrict__ wsn,
                                              f4* __restrict__ out_best,
                                              float* __restrict__ out_idx) {
    const int b = blockIdx.x / 192;
    if (flags[b] == 0) return;          // out_best already written by k_apply
    const int i = blockIdx.x % 192;
    double n = wsn[b];
    double nm = fmax(n, 1.0);
    double best = INFINITY;
    int bc = 0;
    for (int cc = 0; cc < 4; cc++) {
        double mse = (n > 0.0) ? (esum[b * 4 + cc] / nm) : INFINITY;
        if (mse < best) { best = mse; bc = cc; }
    }
    if (i == 0 && threadIdx.x == 0) out_idx[b] = (float)bc;
    const int base = (b * 4 + bc) * HW4 + i * 1024 + threadIdx.x;
    const int obase = b * HW4 + i * 1024 + threadIdx.x;
#pragma unroll
    for (int k = 0; k < 4; k++) {
        f4 v = corr[base + k * 256];
        __builtin_nontemporal_store(v, &out_best[obase + k * 256]);
    }
}

extern "C" void kernel_launch(void* const* d_in, const int* in_sizes, int n_in,
                              void* d_out, int out_size, void* d_ws, size_t ws_size,
                              hipStream_t stream) {
    const f4* nsd = (const f4*)d_in[0];
    const f4* sp  = (const f4*)d_in[1];
    float* out = (float*)d_out;

    float* out_corr = out;                 // 16*4*768*1024
    float* out_best = out + 50331648;      // 16*1*768*1024
    float* out_idx  = out + 62914560;      // 16

    // partials (23*1024 doubles = 184 KB) live inside batch-14's out_best slice;
    // every group's partials are consumed in-kernel (finisher) before A3 overwrites.
    double* part = (double*)(out_best + 14 * HWPIX);

    // d_ws layout: counters[4] @0 | wsf float[128] @64 | wsn double[16] @576
    //              bidx int[16] @704 | flags int[16] @768 | esum double[64] @832
    int*    counter = (int*)d_ws;
    float*  wsf   = (float*)((char*)d_ws + 64);
    double* wsn   = (double*)((char*)d_ws + 576);
    int*    bidx  = (int*)((char*)d_ws + 704);
    int*    flags = (int*)((char*)d_ws + 768);
    double* esum  = (double*)((char*)d_ws + 832);

    hipMemsetAsync(d_ws, 0, 64, stream);   // zero group counters
    for (int g = 0; g < 4; g++) {
        const int g0 = g * NBG;
        k_reduce<<<GBLK, 256, 0, stream>>>(nsd, sp, part, g0, counter,
                                           wsf, wsn, bidx, flags, esum, out_idx);
        k_apply<<<GBLK, 256, 0, stream>>>(nsd, sp, wsf, bidx, flags, esum,
                                          (f4*)out_corr, (f4*)out_best, g0);
    }
    k_best<<<3072, 256, 0, stream>>>((const f4*)out_corr, flags, esum, wsn,
                                     (f4*)out_best, out_idx);
}

// Round 8
// 181.589 us; speedup vs baseline: 2.9784x; 2.9784x over previous
//
#include <hip/hip_runtime.h>

// DepthScaleCorrector — L3-blocked group pipeline (no fences, no atomics).
// nsd (16,4,768,1024) f32, sp (16,1,768,1024) f32.
// Outputs (concat f32): corrected 50331648 | best_corrected 12582912 | best_idx 16.
//
// 16 batches in 4 groups of 4: each group's input (63 MB) stays L3-resident
// between its reduce pass and its apply pass (63R + 63W << 256 MB L3).
// Cross-XCD visibility comes from kernel boundaries (runtime release/acquire),
// NOT per-block fences (round-7 lesson: agent-scope fences serialized everything).
//   k_reduce(g) : 23 masked stats per block -> partials
//   k_solve(g)  : 1 block reduces 23x1024 partials, solves 2x2, analytic MSE +
//                 clip-proof, argmin -> wsf/bidx/flags (fast path decided here)
//   k_apply(g)  : corrected = clip(a*x+b); regular loads (L3-hot), NT stores;
//                 fast path writes out_best inline; slow path exact err atomics
//   k_best      : fast batches early-exit; slow-path fallback argmin + copy

typedef float f4 __attribute__((ext_vector_type(4)));

#define HWPIX (768 * 1024)
#define HW4   (HWPIX / 4)      // 196608 f4 per (b,c)
#define NBG 4                  // batches per group
#define GBLK 1024              // blocks per group dispatch
#define BPB (GBLK / NBG)       // 256 blocks per batch
#define F4PB (HW4 / BPB)       // 768 f4 per (b,c) per block
#define GITERS (F4PB / 256)    // 3
#define VALID_THR 1e-6f
#define MAXD 20.0f
#define NSTAT 23               // 0:n 1:y 2:y2 3+c:x 7+c:x2 11+c:xy 15+c:xmin 19+c:xmax

__device__ inline double wred_sum(double v) {
#pragma unroll
    for (int o = 32; o > 0; o >>= 1) v += __shfl_down(v, o, 64);
    return v;
}

// ---------------- pass 1: masked stats ----------------
__global__ __launch_bounds__(256) void k_reduce(const f4* __restrict__ nsd,
                                                const f4* __restrict__ sp,
                                                double* __restrict__ part,
                                                int g0) {
    const int blk = blockIdx.x;
    const int bl = blk >> 8;            // local batch 0..3
    const int chunk = blk & (BPB - 1);
    const int b = g0 + bl;
    const int t = threadIdx.x;
    const int sbase = b * HW4 + chunk * F4PB;

    float lnv = 0.f, lyv = 0.f, ly2 = 0.f;
    float lx[4] = {0, 0, 0, 0}, lx2[4] = {0, 0, 0, 0}, lxy[4] = {0, 0, 0, 0};
    float lmn[4] = {INFINITY, INFINITY, INFINITY, INFINITY};
    float lmx[4] = {-INFINITY, -INFINITY, -INFINITY, -INFINITY};
#pragma unroll
    for (int i = 0; i < GITERS; i++) {
        const int o = i * 256 + t;
        f4 s4 = sp[sbase + o];
        float mv[4], svm[4];
#pragma unroll
        for (int l = 0; l < 4; l++) {
            float sv = s4[l];
            mv[l] = (sv > VALID_THR && sv <= MAXD) ? 1.0f : 0.0f;
            svm[l] = sv * mv[l];
            lnv += mv[l];
            lyv += svm[l];
            ly2 = fmaf(sv * sv, mv[l], ly2);
        }
#pragma unroll
        for (int c = 0; c < 4; c++) {
            f4 x4 = nsd[(b * 4 + c) * HW4 + chunk * F4PB + o];
#pragma unroll
            for (int l = 0; l < 4; l++) {
                float xv = x4[l];
                lx[c]  = fmaf(xv, mv[l], lx[c]);
                lx2[c] = fmaf(xv * xv, mv[l], lx2[c]);
                lxy[c] = fmaf(xv, svm[l], lxy[c]);
                lmn[c] = fminf(lmn[c], mv[l] != 0.f ? xv : INFINITY);
                lmx[c] = fmaxf(lmx[c], mv[l] != 0.f ? xv : -INFINITY);
            }
        }
    }

    double vals[NSTAT] = {(double)lnv, (double)lyv, (double)ly2,
                          (double)lx[0],  (double)lx[1],  (double)lx[2],  (double)lx[3],
                          (double)lx2[0], (double)lx2[1], (double)lx2[2], (double)lx2[3],
                          (double)lxy[0], (double)lxy[1], (double)lxy[2], (double)lxy[3],
                          (double)lmn[0], (double)lmn[1], (double)lmn[2], (double)lmn[3],
                          (double)lmx[0], (double)lmx[1], (double)lmx[2], (double)lmx[3]};
    __shared__ double red[4][NSTAT];
    const int wv = t >> 6, lane = t & 63;
#pragma unroll
    for (int j = 0; j < NSTAT; j++) {
        double r;
        if (j < 15)      r = wred_sum(vals[j]);
        else if (j < 19) { double v = vals[j];
#pragma unroll
            for (int o = 32; o > 0; o >>= 1) v = fmin(v, __shfl_down(v, o, 64));
            r = v;
        } else { double v = vals[j];
#pragma unroll
            for (int o = 32; o > 0; o >>= 1) v = fmax(v, __shfl_down(v, o, 64));
            r = v;
        }
        if (lane == 0) red[wv][j] = r;
    }
    __syncthreads();
    if (t < NSTAT) {
        double a0 = red[0][t], a1 = red[1][t], a2 = red[2][t], a3 = red[3][t];
        double r = (t < 15) ? (a0 + a1 + a2 + a3)
                 : (t < 19) ? fmin(fmin(a0, a1), fmin(a2, a3))
                            : fmax(fmax(a0, a1), fmax(a2, a3));
        part[t * GBLK + blk] = r;
    }
}

// ---------------- per-group solve ----------------
__global__ void k_solve(const double* __restrict__ part, float* __restrict__ wsf,
                        double* __restrict__ wsn, int* __restrict__ bidx,
                        int* __restrict__ flags, double* __restrict__ esum,
                        float* __restrict__ out_idx, int g0) {
    const int t = threadIdx.x;          // 768 threads; 736 active in stage 1
    __shared__ double sred[NSTAT][NBG];
    __shared__ double smse[NBG][4];
    __shared__ int snoclip[NBG][4];

    if (t < NSTAT * NBG * 8) {          // 736: 8 threads per (stat j, batch bb) task
        const int task = t >> 3, p = t & 7;
        const int j = task >> 2;
        const int bb = task & 3;
        const double* src = part + j * GBLK + bb * BPB + p * 32;
        double acc;
        if (j < 15) {
            acc = 0.0;
#pragma unroll 8
            for (int k = 0; k < 32; k++) acc += src[k];
            acc += __shfl_down(acc, 4, 64);
            acc += __shfl_down(acc, 2, 64);
            acc += __shfl_down(acc, 1, 64);
        } else if (j < 19) {
            acc = INFINITY;
#pragma unroll 8
            for (int k = 0; k < 32; k++) acc = fmin(acc, src[k]);
            acc = fmin(acc, __shfl_down(acc, 4, 64));
            acc = fmin(acc, __shfl_down(acc, 2, 64));
            acc = fmin(acc, __shfl_down(acc, 1, 64));
        } else {
            acc = -INFINITY;
#pragma unroll 8
            for (int k = 0; k < 32; k++) acc = fmax(acc, src[k]);
            acc = fmax(acc, __shfl_down(acc, 4, 64));
            acc = fmax(acc, __shfl_down(acc, 2, 64));
            acc = fmax(acc, __shfl_down(acc, 1, 64));
        }
        if (p == 0) sred[j][bb] = acc;
    }
    __syncthreads();

    if (t < NBG * 4) {                  // 16 threads: (local batch, channel)
        const int bb = t >> 2, c = t & 3;
        const int gb = g0 + bb;
        double n   = sred[0][bb];
        double y   = sred[1][bb];
        double y2  = sred[2][bb];
        double x   = sred[3 + c][bb];
        double x2  = sred[7 + c][bb];
        double xy  = sred[11 + c][bb];
        double xmn = sred[15 + c][bb];
        double xmx = sred[19 + c][bb];
        double det = n * x2 - x * x;
        bool ok = (n >= 10.0) && (fabs(det) >= 1e-8);
        double sdet = ok ? det : 1.0;
        double ad = ok ? (n * xy - x * y) / sdet : 1.0;
        double bd = ok ? (x2 * y - x * xy) / sdet : 0.0;
        float af = (float)ad, bf = (float)bd;
        wsf[gb * 4 + c] = af;
        wsf[64 + gb * 4 + c] = bf;
        if (c == 0) wsn[gb] = n;
        esum[gb * 4 + c] = 0.0;

        double mse;
        int noclip;
        if (n <= 0.0) {
            mse = INFINITY;
            noclip = 1;
        } else {
            double A = (double)af, B = (double)bf;
            double e0 = A * xmn + B, e1 = A * xmx + B;
            double clo = fmin(e0, e1), chi = fmax(e0, e1);
            noclip = (clo >= 0.0 && chi <= (double)MAXD) ? 1 : 0;
            mse = (A * A * x2 + 2.0 * A * B * x + B * B * n
                   - 2.0 * A * xy - 2.0 * B * y + y2) / fmax(n, 1.0);
        }
        smse[bb][c] = mse;
        snoclip[bb][c] = noclip;
    }
    __syncthreads();

    if (t < NBG) {
        const int gb = g0 + t;
        int fast = snoclip[t][0] & snoclip[t][1] & snoclip[t][2] & snoclip[t][3];
        flags[gb] = fast ? 0 : 1;
        if (fast) {
            double best = INFINITY;
            int bc = 0;
            for (int cc = 0; cc < 4; cc++) {
                double m = smse[t][cc];
                if (m < best) { best = m; bc = cc; }
            }
            bidx[gb] = bc;
            out_idx[gb] = (float)bc;
        }
    }
}

// ---------------- pass 2: apply (group) ----------------
__global__ __launch_bounds__(256) void k_apply(const f4* __restrict__ nsd,
                                               const f4* __restrict__ sp,
                                               const float* __restrict__ wsf,
                                               const int* __restrict__ bidx,
                                               const int* __restrict__ flags,
                                               double* __restrict__ esum,
                                               f4* __restrict__ out_corr,
                                               f4* __restrict__ out_best,
                                               int g0) {
    const int blk = blockIdx.x;
    const int bl = blk >> 8;
    const int chunk = blk & (BPB - 1);
    const int b = g0 + bl;
    const int t = threadIdx.x;
    float sc[4], bi[4];
#pragma unroll
    for (int c = 0; c < 4; c++) {
        sc[c] = wsf[b * 4 + c];
        bi[c] = wsf[64 + b * 4 + c];
    }
    const int sbase = b * HW4 + chunk * F4PB;

    if (flags[b] == 0) {
        const int cbest = bidx[b];
#pragma unroll
        for (int i = 0; i < GITERS; i++) {
            const int o = i * 256 + t;
#pragma unroll
            for (int c = 0; c < 4; c++) {
                const int off = (b * 4 + c) * HW4 + chunk * F4PB + o;
                f4 x4 = nsd[off];        // L3-hot: just read by this group's k_reduce
                f4 o4;
#pragma unroll
                for (int l = 0; l < 4; l++)
                    o4[l] = fminf(fmaxf(fmaf(sc[c], x4[l], bi[c]), 0.0f), MAXD);
                __builtin_nontemporal_store(o4, &out_corr[off]);
                if (c == cbest)
                    __builtin_nontemporal_store(o4, &out_best[sbase + o]);
            }
        }
        return;
    }

    // slow path (clipping detected): exact per-pixel err
    float lerr[4] = {0, 0, 0, 0};
#pragma unroll
    for (int i = 0; i < GITERS; i++) {
        const int o = i * 256 + t;
        f4 s4 = sp[sbase + o];
        float mv[4];
#pragma unroll
        for (int l = 0; l < 4; l++)
            mv[l] = (s4[l] > VALID_THR && s4[l] <= MAXD) ? 1.0f : 0.0f;
#pragma unroll
        for (int c = 0; c < 4; c++) {
            const int off = (b * 4 + c) * HW4 + chunk * F4PB + o;
            f4 x4 = nsd[off];
            f4 o4;
#pragma unroll
            for (int l = 0; l < 4; l++)
                o4[l] = fminf(fmaxf(fmaf(sc[c], x4[l], bi[c]), 0.0f), MAXD);
            __builtin_nontemporal_store(o4, &out_corr[off]);
#pragma unroll
            for (int l = 0; l < 4; l++) {
                float d = o4[l] - s4[l];
                lerr[c] = fmaf(d * d, mv[l], lerr[c]);
            }
        }
    }
    __shared__ double red[4][4];
    const int wv = t >> 6, lane = t & 63;
#pragma unroll
    for (int j = 0; j < 4; j++) {
        double r = wred_sum((double)lerr[j]);
        if (lane == 0) red[wv][j] = r;
    }
    __syncthreads();
    if (t < 4)
        atomicAdd(&esum[b * 4 + t], red[0][t] + red[1][t] + red[2][t] + red[3][t]);
}

// ---------------- slow-path best copy ----------------
__global__ __launch_bounds__(256) void k_best(const f4* __restrict__ corr,
                                              const int* __restrict__ flags,
                                              const double* __restrict__ esum,
                                              const double* __restrict__ wsn,
                                              f4* __restrict__ out_best,
                                              float* __restrict__ out_idx) {
    const int b = blockIdx.x / 192;
    if (flags[b] == 0) return;          // out_best already written by k_apply
    const int i = blockIdx.x % 192;
    double n = wsn[b];
    double nm = fmax(n, 1.0);
    double best = INFINITY;
    int bc = 0;
    for (int cc = 0; cc < 4; cc++) {
        double mse = (n > 0.0) ? (esum[b * 4 + cc] / nm) : INFINITY;
        if (mse < best) { best = mse; bc = cc; }
    }
    if (i == 0 && threadIdx.x == 0) out_idx[b] = (float)bc;
    const int base = (b * 4 + bc) * HW4 + i * 1024 + threadIdx.x;
    const int obase = b * HW4 + i * 1024 + threadIdx.x;
#pragma unroll
    for (int k = 0; k < 4; k++) {
        f4 v = corr[base + k * 256];
        __builtin_nontemporal_store(v, &out_best[obase + k * 256]);
    }
}

extern "C" void kernel_launch(void* const* d_in, const int* in_sizes, int n_in,
                              void* d_out, int out_size, void* d_ws, size_t ws_size,
                              hipStream_t stream) {
    const f4* nsd = (const f4*)d_in[0];
    const f4* sp  = (const f4*)d_in[1];
    float* out = (float*)d_out;

    float* out_corr = out;                 // 16*4*768*1024
    float* out_best = out + 50331648;      // 16*1*768*1024
    float* out_idx  = out + 62914560;      // 16

    // partials (23*1024 doubles = 184 KB) live in batch-14's out_best slice;
    // each group's partials are consumed by its k_solve before group 3's
    // k_apply overwrites that slice with real output.
    double* part = (double*)(out_best + 14 * HWPIX);

    // d_ws layout: wsf float[128] @0 | wsn double[16] @512
    //              bidx int[16] @640 | flags int[16] @704 | esum double[64] @768
    float*  wsf   = (float*)d_ws;
    double* wsn   = (double*)((char*)d_ws + 512);
    int*    bidx  = (int*)((char*)d_ws + 640);
    int*    flags = (int*)((char*)d_ws + 704);
    double* esum  = (double*)((char*)d_ws + 768);

    for (int g = 0; g < 4; g++) {
        const int g0 = g * NBG;
        k_reduce<<<GBLK, 256, 0, stream>>>(nsd, sp, part, g0);
        k_solve<<<1, 768, 0, stream>>>(part, wsf, wsn, bidx, flags, esum, out_idx, g0);
        k_apply<<<GBLK, 256, 0, stream>>>(nsd, sp, wsf, bidx, flags, esum,
                                          (f4*)out_corr, (f4*)out_best, g0);
    }
    k_best<<<3072, 256, 0, stream>>>((const f4*)out_corr, flags, esum, wsn,
                                     (f4*)out_best, out_idx);
}

// Round 9
// 128.916 us; speedup vs baseline: 4.1954x; 1.4086x over previous
//
#include <hip/hip_runtime.h>

// DepthScaleCorrector — monolithic 4-dispatch structure (round-6 revert + MRU-first apply).
// nsd (16,4,768,1024) f32, sp (16,1,768,1024) f32.
// Outputs (concat f32): corrected 50331648 | best_corrected 12582912 | best_idx 16.
//
//   k_reduce : 23 masked stats per block (regular loads -> allocate inputs in L3)
//   k_solve  : reduce partials (pair-split), solve 2x2, analytic MSE + clip-proof,
//              argmin -> bidx/flags (fast path decided BEFORE pass 2)
//   k_apply  : corrected = clip(a*x+b); regular loads, NT stores; REVERSE block
//              order (MRU-first under LRU eviction by own write stream);
//              fast path writes out_best inline, no sp read
//   k_best   : fast batches early-exit; slow-path fallback (exact err argmin + copy)

typedef float f4 __attribute__((ext_vector_type(4)));

#define HWPIX (768 * 1024)
#define HW4   (HWPIX / 4)      // 196608 f4 per (b,c)
#define CHUNKS 128             // blocks per batch in the big kernels
#define F4PC  (HW4 / CHUNKS)   // 1536 f4 per chunk per channel
#define ITERS (F4PC / 256)     // 6
#define VALID_THR 1e-6f
#define MAXD 20.0f
#define NPART 2048             // 16*128
#define NSTAT 23               // 0:n 1:y 2:y2 3+c:x 7+c:x2 11+c:xy 15+c:xmin 19+c:xmax

__device__ inline double wred_sum(double v) {
#pragma unroll
    for (int o = 32; o > 0; o >>= 1) v += __shfl_down(v, o, 64);
    return v;
}
__device__ inline double wred_min(double v) {
#pragma unroll
    for (int o = 32; o > 0; o >>= 1) v = fmin(v, __shfl_down(v, o, 64));
    return v;
}
__device__ inline double wred_max(double v) {
#pragma unroll
    for (int o = 32; o > 0; o >>= 1) v = fmax(v, __shfl_down(v, o, 64));
    return v;
}

// ---------------- pass 1: masked stats ----------------
__global__ __launch_bounds__(256) void k_reduce(const f4* __restrict__ nsd,
                                                const f4* __restrict__ sp,
                                                double* __restrict__ part) {
    const int blk = blockIdx.x;
    const int b = blk >> 7;
    const int chunk = blk & (CHUNKS - 1);
    const int t = threadIdx.x;
    const int sbase = b * HW4 + chunk * F4PC;

    float lnv = 0.f, lyv = 0.f, ly2 = 0.f;
    float lx[4] = {0, 0, 0, 0}, lx2[4] = {0, 0, 0, 0}, lxy[4] = {0, 0, 0, 0};
    float lmn[4] = {INFINITY, INFINITY, INFINITY, INFINITY};
    float lmx[4] = {-INFINITY, -INFINITY, -INFINITY, -INFINITY};
#pragma unroll
    for (int i = 0; i < ITERS; i++) {
        const int o = i * 256 + t;
        f4 s4 = sp[sbase + o];
        float mv[4], svm[4];
#pragma unroll
        for (int l = 0; l < 4; l++) {
            float sv = s4[l];
            mv[l] = (sv > VALID_THR && sv <= MAXD) ? 1.0f : 0.0f;
            svm[l] = sv * mv[l];
            lnv += mv[l];
            lyv += svm[l];
            ly2 = fmaf(sv * sv, mv[l], ly2);
        }
#pragma unroll
        for (int c = 0; c < 4; c++) {
            f4 x4 = nsd[(b * 4 + c) * HW4 + chunk * F4PC + o];
#pragma unroll
            for (int l = 0; l < 4; l++) {
                float xv = x4[l];
                lx[c]  = fmaf(xv, mv[l], lx[c]);
                lx2[c] = fmaf(xv * xv, mv[l], lx2[c]);
                lxy[c] = fmaf(xv, svm[l], lxy[c]);
                lmn[c] = fminf(lmn[c], mv[l] != 0.f ? xv : INFINITY);
                lmx[c] = fmaxf(lmx[c], mv[l] != 0.f ? xv : -INFINITY);
            }
        }
    }

    double vals[NSTAT] = {(double)lnv, (double)lyv, (double)ly2,
                          (double)lx[0],  (double)lx[1],  (double)lx[2],  (double)lx[3],
                          (double)lx2[0], (double)lx2[1], (double)lx2[2], (double)lx2[3],
                          (double)lxy[0], (double)lxy[1], (double)lxy[2], (double)lxy[3],
                          (double)lmn[0], (double)lmn[1], (double)lmn[2], (double)lmn[3],
                          (double)lmx[0], (double)lmx[1], (double)lmx[2], (double)lmx[3]};
    __shared__ double red[4][NSTAT];
    const int wv = t >> 6, lane = t & 63;
#pragma unroll
    for (int j = 0; j < NSTAT; j++) {
        double r = (j < 15) ? wred_sum(vals[j])
                 : (j < 19) ? wred_min(vals[j])
                            : wred_max(vals[j]);
        if (lane == 0) red[wv][j] = r;
    }
    __syncthreads();
    if (t < NSTAT) {
        double a0 = red[0][t], a1 = red[1][t], a2 = red[2][t], a3 = red[3][t];
        double r = (t < 15) ? (a0 + a1 + a2 + a3)
                 : (t < 19) ? fmin(fmin(a0, a1), fmin(a2, a3))
                            : fmax(fmax(a0, a1), fmax(a2, a3));
        part[t * NPART + blk] = r;
    }
}

// ---------------- solve + analytic mse + argmin ----------------
__global__ void k_solve(const double* __restrict__ part, float* __restrict__ wsf,
                        double* __restrict__ wsn, int* __restrict__ bidx,
                        int* __restrict__ flags, double* __restrict__ esum,
                        float* __restrict__ out_idx) {
    const int t = threadIdx.x;          // 768 threads; 736 active in stage 1
    __shared__ double sred[NSTAT][16];
    __shared__ double smse[64];
    __shared__ int snoclip[64];

    if (t < NSTAT * 32) {               // pair-split: 2 threads per (j,b) task
        const int j = t >> 5;           // stat
        const int rem = t & 31;
        const int b = rem >> 1;         // batch
        const int p = rem & 1;          // half
        const double* src = part + j * NPART + b * CHUNKS + p * 64;
        double acc;
        if (j < 15) {
            acc = 0.0;
#pragma unroll 8
            for (int k = 0; k < 64; k++) acc += src[k];
            acc += __shfl_down(acc, 1, 64);
        } else if (j < 19) {
            acc = INFINITY;
#pragma unroll 8
            for (int k = 0; k < 64; k++) acc = fmin(acc, src[k]);
            acc = fmin(acc, __shfl_down(acc, 1, 64));
        } else {
            acc = -INFINITY;
#pragma unroll 8
            for (int k = 0; k < 64; k++) acc = fmax(acc, src[k]);
            acc = fmax(acc, __shfl_down(acc, 1, 64));
        }
        if (p == 0) sred[j][b] = acc;
    }
    __syncthreads();

    if (t < 64) {
        const int b = t >> 2, c = t & 3;
        double n   = sred[0][b];
        double y   = sred[1][b];
        double y2  = sred[2][b];
        double x   = sred[3 + c][b];
        double x2  = sred[7 + c][b];
        double xy  = sred[11 + c][b];
        double xmn = sred[15 + c][b];
        double xmx = sred[19 + c][b];
        double det = n * x2 - x * x;
        bool ok = (n >= 10.0) && (fabs(det) >= 1e-8);
        double sdet = ok ? det : 1.0;
        double ad = ok ? (n * xy - x * y) / sdet : 1.0;
        double bd = ok ? (x2 * y - x * xy) / sdet : 0.0;
        float af = (float)ad, bf = (float)bd;
        wsf[t] = af;
        wsf[64 + t] = bf;
        if (c == 0) wsn[b] = n;
        esum[t] = 0.0;

        double mse;
        int noclip;
        if (n <= 0.0) {
            mse = INFINITY;
            noclip = 1;
        } else {
            double A = (double)af, B = (double)bf;
            double e0 = A * xmn + B, e1 = A * xmx + B;
            double clo = fmin(e0, e1), chi = fmax(e0, e1);
            noclip = (clo >= 0.0 && chi <= (double)MAXD) ? 1 : 0;
            mse = (A * A * x2 + 2.0 * A * B * x + B * B * n
                   - 2.0 * A * xy - 2.0 * B * y + y2) / fmax(n, 1.0);
        }
        smse[t] = mse;
        snoclip[t] = noclip;
    }
    __syncthreads();

    if (t < 16) {
        int fast = snoclip[t * 4] & snoclip[t * 4 + 1] & snoclip[t * 4 + 2] & snoclip[t * 4 + 3];
        flags[t] = fast ? 0 : 1;
        if (fast) {
            double best = INFINITY;
            int bc = 0;
            for (int cc = 0; cc < 4; cc++) {
                double m = smse[t * 4 + cc];
                if (m < best) { best = m; bc = cc; }
            }
            bidx[t] = bc;
            out_idx[t] = (float)bc;
        }
    }
}

// ---------------- pass 2: apply (+ exact err only if clipping detected) ----------------
__global__ __launch_bounds__(256) void k_apply(const f4* __restrict__ nsd,
                                               const f4* __restrict__ sp,
                                               const float* __restrict__ wsf,
                                               const int* __restrict__ bidx,
                                               const int* __restrict__ flags,
                                               double* __restrict__ esum,
                                               f4* __restrict__ out_corr,
                                               f4* __restrict__ out_best) {
    // Reverse block order: read MRU-first relative to k_reduce's allocation order,
    // so the newest L3-resident input lines are consumed before this kernel's own
    // write stream evicts from the LRU tail.
    const int blk = (NPART - 1) - blockIdx.x;
    const int b = blk >> 7;
    const int chunk = blk & (CHUNKS - 1);
    const int t = threadIdx.x;
    float sc[4], bi[4];
#pragma unroll
    for (int c = 0; c < 4; c++) {
        sc[c] = wsf[b * 4 + c];
        bi[c] = wsf[64 + b * 4 + c];
    }
    const int sbase = b * HW4 + chunk * F4PC;

    if (flags[b] == 0) {
        const int cbest = bidx[b];
#pragma unroll
        for (int i = 0; i < ITERS; i++) {
            const int o = i * 256 + t;
#pragma unroll
            for (int c = 0; c < 4; c++) {
                const int off = (b * 4 + c) * HW4 + chunk * F4PC + o;
                f4 x4 = nsd[off];
                f4 o4;
#pragma unroll
                for (int l = 0; l < 4; l++)
                    o4[l] = fminf(fmaxf(fmaf(sc[c], x4[l], bi[c]), 0.0f), MAXD);
                __builtin_nontemporal_store(o4, &out_corr[off]);
                if (c == cbest)
                    __builtin_nontemporal_store(o4, &out_best[sbase + o]);
            }
        }
        return;
    }

    // slow path (a masked pixel would clip): exact per-pixel err
    float lerr[4] = {0, 0, 0, 0};
#pragma unroll
    for (int i = 0; i < ITERS; i++) {
        const int o = i * 256 + t;
        f4 s4 = sp[sbase + o];
        float mv[4];
#pragma unroll
        for (int l = 0; l < 4; l++)
            mv[l] = (s4[l] > VALID_THR && s4[l] <= MAXD) ? 1.0f : 0.0f;
#pragma unroll
        for (int c = 0; c < 4; c++) {
            const int off = (b * 4 + c) * HW4 + chunk * F4PC + o;
            f4 x4 = nsd[off];
            f4 o4;
#pragma unroll
            for (int l = 0; l < 4; l++)
                o4[l] = fminf(fmaxf(fmaf(sc[c], x4[l], bi[c]), 0.0f), MAXD);
            __builtin_nontemporal_store(o4, &out_corr[off]);
#pragma unroll
            for (int l = 0; l < 4; l++) {
                float d = o4[l] - s4[l];
                lerr[c] = fmaf(d * d, mv[l], lerr[c]);
            }
        }
    }
    __shared__ double red[4][4];
    const int wv = t >> 6, lane = t & 63;
#pragma unroll
    for (int j = 0; j < 4; j++) {
        double r = wred_sum((double)lerr[j]);
        if (lane == 0) red[wv][j] = r;
    }
    __syncthreads();
    if (t < 4)
        atomicAdd(&esum[b * 4 + t], red[0][t] + red[1][t] + red[2][t] + red[3][t]);
}

// ---------------- slow-path best copy ----------------
__global__ __launch_bounds__(256) void k_best(const f4* __restrict__ corr,
                                              const int* __restrict__ flags,
                                              const double* __restrict__ esum,
                                              const double* __restrict__ wsn,
                                              f4* __restrict__ out_best,
                                              float* __restrict__ out_idx) {
    const int b = blockIdx.x / 192;
    if (flags[b] == 0) return;          // out_best already written by k_apply
    const int i = blockIdx.x % 192;
    double n = wsn[b];
    double nm = fmax(n, 1.0);
    double best = INFINITY;
    int bc = 0;
    for (int cc = 0; cc < 4; cc++) {
        double mse = (n > 0.0) ? (esum[b * 4 + cc] / nm) : INFINITY;
        if (mse < best) { best = mse; bc = cc; }
    }
    if (i == 0 && threadIdx.x == 0) out_idx[b] = (float)bc;
    const int base = (b * 4 + bc) * HW4 + i * 1024 + threadIdx.x;
    const int obase = b * HW4 + i * 1024 + threadIdx.x;
#pragma unroll
    for (int k = 0; k < 4; k++) {
        f4 v = corr[base + k * 256];
        __builtin_nontemporal_store(v, &out_best[obase + k * 256]);
    }
}

extern "C" void kernel_launch(void* const* d_in, const int* in_sizes, int n_in,
                              void* d_out, int out_size, void* d_ws, size_t ws_size,
                              hipStream_t stream) {
    const f4* nsd = (const f4*)d_in[0];
    const f4* sp  = (const f4*)d_in[1];
    float* out = (float*)d_out;

    float* out_corr = out;                 // 16*4*768*1024
    float* out_best = out + 50331648;      // 16*1*768*1024
    float* out_idx  = out + 62914560;      // 16

    // pass-1 partials live in the out_best region (consumed by k_solve before
    // k_apply/k_best write real data there)
    double* part = (double*)out_best;      // 23*2048 doubles = 368 KB

    // tiny cross-kernel state in d_ws (~1.3 KB)
    float*  wsf   = (float*)d_ws;                    // scale[64], bias[64]
    double* wsn   = (double*)((char*)d_ws + 512);    // n[16]
    int*    bidx  = (int*)((char*)d_ws + 640);       // best idx[16]
    int*    flags = (int*)((char*)d_ws + 704);       // slow-path flags[16]
    double* esum  = (double*)((char*)d_ws + 768);    // exact err sums[64]

    k_reduce<<<NPART, 256, 0, stream>>>(nsd, sp, part);
    k_solve<<<1, 768, 0, stream>>>(part, wsf, wsn, bidx, flags, esum, out_idx);
    k_apply<<<NPART, 256, 0, stream>>>(nsd, sp, wsf, bidx, flags, esum,
                                       (f4*)out_corr, (f4*)out_best);
    k_best<<<3072, 256, 0, stream>>>((const f4*)out_corr, flags, esum, wsn,
                                     (f4*)out_best, out_idx);
}